// Round 3
// baseline (154.573 us; speedup 1.0000x reference)
//
#include <hip/hip_runtime.h>
#include <math.h>

#define NROWS 8192
#define HALF  4096
#define EMB   2048
#define DIM   256
#define INV_T 10.0f

typedef __bf16 bf16x8v __attribute__((ext_vector_type(8)));
typedef __bf16 bf16x4v __attribute__((ext_vector_type(4)));
typedef float  f32x4   __attribute__((ext_vector_type(4)));

__device__ __forceinline__ void gld_lds16(const void* g, void* l) {
    __builtin_amdgcn_global_load_lds((const __attribute__((address_space(1))) void*)g,
                                     (__attribute__((address_space(3))) void*)l,
                                     16, 0, 0);
}

// ---------- K0: W [2048][256] f32 -> Wt [256][2048] bf16, coalesced tile transpose ----------
__global__ __launch_bounds__(256) void wt_kernel(const float* __restrict__ W,
                                                 __bf16* __restrict__ Wt) {
    __shared__ __bf16 t[64][72];
    const int n0 = blockIdx.x * 64;
    const int k0 = blockIdx.y * 64;
    const int tid = threadIdx.x;
    const int c = tid & 63;
    const int rr = tid >> 6;
#pragma unroll
    for (int it = 0; it < 16; it++) {
        int k = it * 4 + rr;
        t[k][c] = (__bf16)W[(size_t)(k0 + k) * DIM + n0 + c];
    }
    __syncthreads();
#pragma unroll
    for (int it = 0; it < 16; it++) {
        int n = it * 4 + rr;
        Wt[(size_t)(n0 + n) * EMB + k0 + c] = t[c][n];
    }
}

// ---------- K1: fused GEMM + bias + L2-normalize, emit bf16 X ----------
// v3: 256 blocks x 512 threads (8 waves = 2/SIMD). 32 rows x 256 cols, BK=64.
// Reg-staged double-buffered LDS, A and B both prefetched 2 iters ahead
// (covers HBM ~900cy / L3 ~600cy with two iterations of compute+issue).
// Granule-XOR swizzle (slot g ^ (row&7)) on both ds_write and ds_read sides.
#define FR   32              // rows per block
#define FBK  64              // k per iteration
#define FNIT (EMB / FBK)     // 32

__global__ __launch_bounds__(512) void gemm_norm_fused(
    const float* __restrict__ A,      // [8192][2048] f32
    const __bf16* __restrict__ Wt,    // [256][2048] bf16
    const float* __restrict__ bias,   // [256] f32
    __bf16* __restrict__ outb)        // [8192][256] bf16 normalized
{
    __shared__ __bf16 b_sh[2][DIM][FBK];  // 64 KB
    __shared__ __bf16 a_sh[2][FR][FBK];   // 8 KB
    __shared__ float  red[FR][4];
    __shared__ float  inv_sh[FR];

    const int tid  = threadIdx.x;
    const int wave = tid >> 6, lane = tid & 63;
    const int quad = lane >> 4, l15 = lane & 15;
    const int rowBase = blockIdx.x * FR;
    const int wr = wave >> 2;   // 0..1: row half (16 rows)
    const int wc = wave & 3;    // 0..3: col quarter (64 cols)

    // A staging: thread -> row tid>>4 (0..31), 4-float granule tid&15
    const int arow = tid >> 4;
    const int akq  = tid & 15;
    const float* aPtr = A + (size_t)(rowBase + arow) * EMB + akq * 4;
    const int aoff = (((akq >> 1) ^ (arow & 7)) * 8) + (akq & 1) * 4;  // bf16 units
    // B staging: thread -> col tid>>1, granules (tid&1)*4 + 0..3
    const int bcol = tid >> 1;
    const int bg0  = (tid & 1) * 4;
    const __bf16* bPtr = Wt + (size_t)bcol * EMB + bg0 * 8;

    f32x4 acc[4];
    const f32x4 zero = {0.f, 0.f, 0.f, 0.f};
#pragma unroll
    for (int n = 0; n < 4; n++) acc[n] = zero;

    float bv[4];
#pragma unroll
    for (int n = 0; n < 4; n++) bv[n] = bias[wc * 64 + n * 16 + l15];

    f32x4   aP[2];
    bf16x8v bP[2][4];

    // ---- prologue: tile 0 -> LDS0; issue tile 1 into slot 1 ----
    {
        aP[0] = *(const f32x4*)aPtr;
#pragma unroll
        for (int i = 0; i < 4; i++) bP[0][i] = *(const bf16x8v*)(bPtr + i * 8);
        bf16x4v av;
#pragma unroll
        for (int j = 0; j < 4; j++) av[j] = (__bf16)aP[0][j];
        *(bf16x4v*)&a_sh[0][arow][aoff] = av;
#pragma unroll
        for (int i = 0; i < 4; i++)
            *(bf16x8v*)&b_sh[0][bcol][(((bg0 + i) ^ (bcol & 7)) * 8)] = bP[0][i];
        aP[1] = *(const f32x4*)(aPtr + FBK);
#pragma unroll
        for (int i = 0; i < 4; i++) bP[1][i] = *(const bf16x8v*)(bPtr + FBK + i * 8);
    }
    __syncthreads();

    // ---- main loop ----
#pragma unroll 2
    for (int t = 0; t < FNIT; t++) {
        const int p = t & 1;
        // issue tile t+2 into slot p (its previous content was consumed last iter)
        if (t + 2 < FNIT) {
            aP[p] = *(const f32x4*)(aPtr + (t + 2) * FBK);
#pragma unroll
            for (int i = 0; i < 4; i++)
                bP[p][i] = *(const bf16x8v*)(bPtr + (t + 2) * FBK + i * 8);
        }
        // compute LDS[p]
#pragma unroll
        for (int ks = 0; ks < 2; ks++) {
            const int row  = wr * 16 + l15;
            bf16x8v af = *(const bf16x8v*)&a_sh[p][row][(((ks * 4 + quad) ^ (row & 7)) * 8)];
#pragma unroll
            for (int n = 0; n < 4; n++) {
                const int col = wc * 64 + n * 16 + l15;
                bf16x8v bfv = *(const bf16x8v*)&b_sh[p][col][(((ks * 4 + quad) ^ (col & 7)) * 8)];
                acc[n] = __builtin_amdgcn_mfma_f32_16x16x32_bf16(af, bfv, acc[n], 0, 0, 0);
            }
        }
        // write tile t+1 (issued 2 iters ago -> loads long returned; counted vmcnt)
        if (t + 1 < FNIT) {
            bf16x4v av;
#pragma unroll
            for (int j = 0; j < 4; j++) av[j] = (__bf16)aP[p ^ 1][j];
            *(bf16x4v*)&a_sh[p ^ 1][arow][aoff] = av;
#pragma unroll
            for (int i = 0; i < 4; i++)
                *(bf16x8v*)&b_sh[p ^ 1][bcol][(((bg0 + i) ^ (bcol & 7)) * 8)] = bP[p ^ 1][i];
        }
        __syncthreads();
    }

    // ---- epilogue: bias + row L2-norm + bf16 store ----
    float ss[4];
#pragma unroll
    for (int r = 0; r < 4; r++) {
        float s = 0.f;
#pragma unroll
        for (int n = 0; n < 4; n++) {
            float v = acc[n][r] + bv[n];
            s += v * v;
        }
        ss[r] = s;
    }
#pragma unroll
    for (int off = 1; off < 16; off <<= 1)
#pragma unroll
        for (int r = 0; r < 4; r++) ss[r] += __shfl_xor(ss[r], off, 64);
    if (l15 == 0) {
#pragma unroll
        for (int r = 0; r < 4; r++) red[wr * 16 + quad * 4 + r][wc] = ss[r];
    }
    __syncthreads();
    if (tid < FR) {
        float s = red[tid][0] + red[tid][1] + red[tid][2] + red[tid][3];
        inv_sh[tid] = 1.f / fmaxf(sqrtf(s), 1e-12f);
    }
    __syncthreads();
#pragma unroll
    for (int r = 0; r < 4; r++) {
        const int row = wr * 16 + quad * 4 + r;
        const float iv = inv_sh[row];
#pragma unroll
        for (int n = 0; n < 4; n++) {
            float v = acc[n][r] + bv[n];
            outb[(size_t)(rowBase + row) * DIM + wc * 64 + n * 16 + l15] = (__bf16)(v * iv);
        }
    }
}

// ---------- K2: sim = X@X^T. BK=64 streaming (32 KB LDS -> 3+ blocks/CU),
//              XOR-swizzled staging, shuffle-free unique-writer LDS epilogue, upper-tri grid ----------
#define TILE 128
#define NTILE (NROWS / TILE)              // 64
#define NBLK  (NTILE * (NTILE + 1) / 2)   // 2080

__global__ __launch_bounds__(256, 3) void sim_kernel(
    const __bf16* __restrict__ X,
    float* __restrict__ total,
    float* __restrict__ posv)
{
    __shared__ __align__(16) char smem[32768];
    __bf16* a_base = (__bf16*)smem;            // [2][128][32]
    __bf16* b_base = (__bf16*)(smem + 16384);  // [2][128][32]
    float*  rs     = (float*)smem;             // [128][2][16] = 16 KB
    float*  cs     = (float*)(smem + 16384);   // [128][2][4]  = 4 KB

    const int t = blockIdx.x;
    int bx = (int)((129.0 - sqrt(16641.0 - 8.0 * (double)t)) * 0.5);
    while (64 * (bx + 1) - ((bx + 1) * bx) / 2 <= t) bx++;
    while (64 * bx - (bx * (bx - 1)) / 2 > t) bx--;
    const int by = bx + (t - (64 * bx - (bx * (bx - 1)) / 2));
    const bool diag = (bx == by);

    const int tid  = threadIdx.x;
    const int wave = tid >> 6, lane = tid & 63;
    const int quad = lane >> 4, l15 = lane & 15;
    const int rowBase = bx * TILE;
    const int colBase = by * TILE;
    const int waveRow = (wave >> 1) * 64;
    const int waveCol = (wave & 1) * 64;

    f32x4 acc[4][4];
    const f32x4 zero = {0.f, 0.f, 0.f, 0.f};
#pragma unroll
    for (int m = 0; m < 4; m++)
#pragma unroll
        for (int n = 0; n < 4; n++) acc[m][n] = zero;

    const int r16 = lane >> 2;
    const int b4  = lane & 3;
    const int sw  = (r16 >> 1) & 3;   // stage-side swizzle
    const int sr  = (l15 >> 1) & 3;   // read-side swizzle

    for (int k0 = 0; k0 < DIM; k0 += 64) {
        __syncthreads();
#pragma unroll
        for (int c = 0; c < 2; c++) {
#pragma unroll
            for (int j = 0; j < 2; j++) {
                int rg = wave * 2 + j;   // row-group 0..7
                const __bf16* asrc = X + (size_t)(rowBase + rg * 16 + r16) * DIM + k0 + c * 32 + (b4 ^ sw) * 8;
                const __bf16* bsrc = X + (size_t)(colBase + rg * 16 + r16) * DIM + k0 + c * 32 + (b4 ^ sw) * 8;
                gld_lds16(asrc, a_base + (c * TILE + rg * 16) * 32);
                gld_lds16(bsrc, b_base + (c * TILE + rg * 16) * 32);
            }
        }
        __syncthreads();
#pragma unroll
        for (int ks = 0; ks < 2; ks++) {
            bf16x8v af[4], bfv[4];
#pragma unroll
            for (int m = 0; m < 4; m++)
                af[m] = *(const bf16x8v*)(a_base + (ks * TILE + waveRow + m * 16 + l15) * 32 + (quad ^ sr) * 8);
#pragma unroll
            for (int n = 0; n < 4; n++)
                bfv[n] = *(const bf16x8v*)(b_base + (ks * TILE + waveCol + n * 16 + l15) * 32 + (quad ^ sr) * 8);
#pragma unroll
            for (int m = 0; m < 4; m++)
#pragma unroll
                for (int n = 0; n < 4; n++)
                    acc[m][n] = __builtin_amdgcn_mfma_f32_16x16x32_bf16(af[m], bfv[n], acc[m][n], 0, 0, 0);
        }
    }

    float es[4][4];
    float ecol[4];
#pragma unroll
    for (int n = 0; n < 4; n++) ecol[n] = 0.f;
#pragma unroll
    for (int m = 0; m < 4; m++) {
#pragma unroll
        for (int r = 0; r < 4; r++) {
            int grow = rowBase + waveRow + m * 16 + quad * 4 + r;
            float e_acc = 0.f;
#pragma unroll
            for (int n = 0; n < 4; n++) {
                int gcol = colBase + waveCol + n * 16 + l15;
                float s = acc[m][n][r];
                if (gcol - grow == HALF) { posv[grow] = s; posv[gcol] = s; }
                float e = (gcol == grow) ? 0.f : __expf(s * INV_T);
                e_acc += e;
                ecol[n] += e;
            }
            es[m][r] = e_acc;
        }
    }

    __syncthreads();
    const int wc = wave & 1;
    const int wr = wave >> 1;
#pragma unroll
    for (int m = 0; m < 4; m++)
#pragma unroll
        for (int r = 0; r < 4; r++) {
            int lrow = waveRow + m * 16 + quad * 4 + r;
            rs[(lrow * 2 + wc) * 16 + l15] = es[m][r];
        }
    if (!diag) {
#pragma unroll
        for (int n = 0; n < 4; n++) {
            int lcol = waveCol + n * 16 + l15;
            cs[(lcol * 2 + wr) * 4 + quad] = ecol[n];
        }
    }
    __syncthreads();

    if (tid < TILE) {
        float rsum = 0.f;
#pragma unroll
        for (int i = 0; i < 32; i++) rsum += rs[tid * 32 + i];
        atomicAdd(&total[rowBase + tid], rsum);
        if (!diag) {
            float csum = 0.f;
#pragma unroll
            for (int i = 0; i < 8; i++) csum += cs[tid * 8 + i];
            atomicAdd(&total[colBase + tid], csum);
        }
    }
}

// ---------- K3: loss ----------
__global__ __launch_bounds__(256) void loss_kernel(
    const float* __restrict__ total, const float* __restrict__ posv,
    float* __restrict__ out)
{
    __shared__ float red[4];
    const int tid = threadIdx.x;
    const int i = blockIdx.x * 256 + tid;
    float s = posv[i] * INV_T - __logf(total[i]);
#pragma unroll
    for (int off = 1; off < 64; off <<= 1) s += __shfl_xor(s, off, 64);
    if ((tid & 63) == 0) red[tid >> 6] = s;
    __syncthreads();
    if (tid == 0) {
        float v = red[0] + red[1] + red[2] + red[3];
        atomicAdd(out, -v / (float)NROWS);
    }
}

extern "C" void kernel_launch(void* const* d_in, const int* in_sizes, int n_in,
                              void* d_out, int out_size, void* d_ws, size_t ws_size,
                              hipStream_t stream) {
    const float* emb  = (const float*)d_in[0];
    const float* W    = (const float*)d_in[1];
    const float* bias = (const float*)d_in[2];
    float* out = (float*)d_out;

    char* ws = (char*)d_ws;
    __bf16* outb  = (__bf16*)ws;                          // 4 MB
    __bf16* Wt    = (__bf16*)(ws + (4u << 20));           // 1 MB
    float*  total = (float*)(ws + (5u << 20));            // 32 KB
    float*  posv  = (float*)(ws + (5u << 20) + (32u << 10));

    hipMemsetAsync(total, 0, NROWS * sizeof(float), stream);
    hipMemsetAsync(out, 0, sizeof(float), stream);

    wt_kernel<<<dim3(DIM / 64, EMB / 64), 256, 0, stream>>>(W, Wt);
    gemm_norm_fused<<<dim3(NROWS / FR), 512, 0, stream>>>(emb, Wt, bias, outb);
    sim_kernel<<<dim3(NBLK), 256, 0, stream>>>(outb, total, posv);
    loss_kernel<<<dim3(NROWS / 256), 256, 0, stream>>>(total, posv, out);
}